// Round 11
// baseline (781.106 us; speedup 1.0000x reference)
//
#include <hip/hip_runtime.h>
#include <hip/hip_bf16.h>

#define Bb 8
#define Tt 600
#define Cc 8
#define Ff 257
#define TAPS 5
#define DELAY 3
#define KC 40            // TAPS*C
#define NC 48            // KC + C (R columns | P columns)
#define RPW 51           // RP row stride (float2): 102 dw, gcd(102%32=6,32)=2 -> 16-bank spread
#define TQ 593           // T - DELAY - TAPS + 1
#define TP 606           // Yl row stride (float2): d*28%32 all-distinct, conflict-free; even for float4 staging
#define WLN 604          // wl2 with zero pads [600..603] (max read index 603)
#define AEND 597         // TQ + 4: lag-product a-range
#define EPSF 1e-10f
#define NTOT (Bb*Tt*Cc*Ff)   // 9,868,800

// Native 2-float vector so the backend emits v_pk_fma_f32 (VOP3P packed FP32).
typedef float v2f __attribute__((ext_vector_type(2)));

#if __has_builtin(__builtin_elementwise_fma)
#define PKFMA(a, b, c) __builtin_elementwise_fma((a), (b), (c))
#else
__device__ __forceinline__ v2f pkfma_(v2f a, v2f b, v2f c) {
  v2f r; r.x = fmaf(a.x, b.x, c.x); r.y = fmaf(a.y, b.y, c.y); return r;
}
#define PKFMA(a, b, c) pkfma_((a), (b), (c))
#endif

// p = conj(yd)*yv with yd pre-split: ydxx = yd.xx, ydn = (yd.y, -yd.y)
__device__ __forceinline__ v2f conjmul2(v2f ydxx, v2f ydn, v2f yv) {
  return PKFMA(ydn, yv.yx, ydxx * yv);
}

// Lower-triangle tap-block tables: id -> (k,l), grouped by lag tau=k-l.
constexpr int kABASE[5] = {0, 5, 9, 12, 14};
constexpr int kK15[15] = {0,1,2,3,4, 1,2,3,4, 2,3,4, 3,4, 4};
constexpr int kL15[15] = {0,1,2,3,4, 0,1,2,3, 0,1,2, 0,1, 0};

// (B,T,C,F) re/im planes -> (B,F,C,T) interleaved float2
__global__ __launch_bounds__(256) void k_tin(const float* __restrict__ in_re,
                                             const float* __restrict__ in_im,
                                             float2* __restrict__ Yt) {
  __shared__ float2 tile[32][33];
  int f0 = blockIdx.x * 32, t0 = blockIdx.y * 32;
  int b = blockIdx.z >> 3, c = blockIdx.z & 7;
  int tx = threadIdx.x & 31, ty = threadIdx.x >> 5;
#pragma unroll
  for (int ii = 0; ii < 4; ++ii) {
    int t = t0 + ty + 8 * ii, f = f0 + tx;
    if (t < Tt && f < Ff) {
      size_t idx = (((size_t)b * Tt + t) * Cc + c) * Ff + f;
      tile[ty + 8 * ii][tx] = make_float2(in_re[idx], in_im[idx]);
    }
  }
  __syncthreads();
#pragma unroll
  for (int ii = 0; ii < 4; ++ii) {
    int f = f0 + ty + 8 * ii, t = t0 + tx;
    if (f < Ff && t < Tt) {
      size_t o = (((size_t)b * Ff + f) * Cc + c) * Tt + t;
      Yt[o] = tile[tx][ty + 8 * ii];
    }
  }
}

// Lag-product accumulation (packed).  Two lag-sets across wave pairs:
//   SET 0: tau 0..2 -> 12 R-blocks;  SET 1: tau 3..7 -> 3 R-blocks + 5 P.
// w comes from a RING of 8 register pairs (1 LDS load/a-step instead of 5;
// &7 indices fold at compile time under the 8x unroll since i steps by 8).
// Ring invariant: slot s holds wl2[aA + i + s'] where s' == s (mod 8) and the
// value is the most recent write; window a+3..a+7 spans <= 8 -> always valid.
// Zero-padded wl2 ([0..6], [600..603]) + Yl tail zeros make range ends vanish.
template<int SET>
__device__ __forceinline__ void accum_lag(const v2f* __restrict__ Yd,
                                          const v2f* __restrict__ Ye,
                                          const v2f* __restrict__ wl2,
                                          int aA, int aB,
                                          v2f (&racu)[12], v2f (&pac)[5]) {
  constexpr int YEM = (SET == 0) ? 3 : 7;   // ye ring mask (span 4 / span 8)
  v2f ye[YEM + 1];
  v2f w8r[8];
  if constexpr (SET == 0) {
#pragma unroll
    for (int j = 0; j < 3; ++j) ye[j] = Ye[aA + j];
  } else {
#pragma unroll
    for (int j = 3; j < 7; ++j) ye[j & YEM] = Ye[aA + j];
  }
#pragma unroll
  for (int j = 3; j < 7; ++j) w8r[j & 7] = wl2[aA + j];

  int len = aB - aA;
  int i = 0;
  for (; i + 8 <= len; i += 8) {
#pragma unroll
    for (int u = 0; u < 8; ++u) {            // full unroll: all &-indices fold
      int a_ = aA + i + u;
      v2f yd_ = Yd[a_];
      w8r[(u + 7) & 7] = wl2[a_ + 7];
      v2f ydxx = yd_.xx;
      v2f ydn; ydn.x = yd_.y; ydn.y = -yd_.y;
      if constexpr (SET == 0) {
        ye[(u + 3) & YEM] = Ye[a_ + 3];
#pragma unroll
        for (int tau = 0; tau <= 2; ++tau) {
          v2f p = conjmul2(ydxx, ydn, ye[(u + tau) & YEM]);
#pragma unroll
          for (int k = tau; k < 5; ++k) {
            int id = kABASE[tau] + (k - tau);
            racu[id] = PKFMA(w8r[(u + 3 + k) & 7], p, racu[id]);
          }
        }
      } else {
        ye[(u + 7) & YEM] = Ye[a_ + 7];
#pragma unroll
        for (int tau = 3; tau <= 7; ++tau) {
          v2f p = conjmul2(ydxx, ydn, ye[(u + tau) & YEM]);
          if (tau == 3) {
            racu[0] = PKFMA(w8r[(u + 6) & 7], p, racu[0]);   // id 12: (3,0)
            racu[1] = PKFMA(w8r[(u + 7) & 7], p, racu[1]);   // id 13: (4,1)
          }
          if (tau == 4) racu[2] = PKFMA(w8r[(u + 7) & 7], p, racu[2]);  // id 14
          pac[tau - 3] = PKFMA(w8r[(u + tau) & 7], p, pac[tau - 3]);
        }
      }
    }
  }
  for (; i < len; ++i) {                     // tail <=7: direct LDS reads
    int a = aA + i;
    v2f yd = Yd[a];
    v2f ydxx = yd.xx;
    v2f ydn; ydn.x = yd.y; ydn.y = -yd.y;
    if constexpr (SET == 0) {
#pragma unroll
      for (int tau = 0; tau <= 2; ++tau) {
        v2f p = conjmul2(ydxx, ydn, Ye[a + tau]);
#pragma unroll
        for (int k = tau; k < 5; ++k) {
          int id = kABASE[tau] + (k - tau);
          racu[id] = PKFMA(wl2[a + 3 + k], p, racu[id]);
        }
      }
    } else {
#pragma unroll
      for (int tau = 3; tau <= 7; ++tau) {
        v2f p = conjmul2(ydxx, ydn, Ye[a + tau]);
        if (tau == 3) {
          racu[0] = PKFMA(wl2[a + 6], p, racu[0]);
          racu[1] = PKFMA(wl2[a + 7], p, racu[1]);
        }
        if (tau == 4) racu[2] = PKFMA(wl2[a + 7], p, racu[2]);
        pac[tau - 3] = PKFMA(wl2[a + tau], p, pac[tau - 3]);
      }
    }
  }
}

// One block (512 thr) per (b,f): full 2-iteration WPE.
// Accumulation: 8 waves = 4 a-groups x 2 lag-sets, packed FP32, w-ring;
// apply: 2 threads per t (4 channels each) for 1.28x-balanced load; packed
// sign-prepped solve (2 pk_fma per row element).  enh aliases Yt.
__global__ void __launch_bounds__(512, 4)
__attribute__((amdgpu_waves_per_eu(4, 4)))
k_wpe(const float2* __restrict__ Yt,
      float2* __restrict__ enh,
      const float* __restrict__ in_re,
      const float* __restrict__ in_im,
      const int* __restrict__ ilens,
      float* __restrict__ out_re,
      float* __restrict__ out_im,
      int load_direct, int store_direct) {
  __shared__ float2 Yl[Cc][TP];        // 8 x 606 complex = 38784 B
  __shared__ float2 RP[KC][RPW];       // [R | P] 40 x 51  = 16320 B
  __shared__ float2 wl2s[WLN];         // (w,w) pairs       =  4832 B
  __shared__ float4 Gp[KC][Cc];        // packed filter     =  5120 B -> 65056 B

  // XCD-chunked bijective swizzle (2056 % 8 == 0): bf = (orig%8)*257 + orig/8
  int orig = blockIdx.x;
  int bf = (orig & 7) * (Bb * Ff / 8) + (orig >> 3);
  int b = bf / Ff, f = bf % Ff;
  int tid = threadIdx.x;               // 0..511
  int group = tid >> 6;                // wave id
  int lane = tid & 63;
  int d = lane & 7;                    // row channel
  int e = lane >> 3;                   // col channel
  int tg = group >> 1;                 // a-group 0..3
  int ls = group & 1;                  // lag-set: 0 -> tau 0..2, 1 -> tau 3..7

  // apply mapping: 2 threads per t, 4 output channels each
  int ah = tid & 1;                    // channel half: ee in [4*ah, 4*ah+4)
  int at2 = tid >> 1;                  // t-stripe 0..255

  // solve mapping: thread = (row, col-chunk), 480 active
  int srow = tid % KC;                 // const divisor -> magic mul, hoisted
  int scol = tid / KC;                 // 0..12

  // ---- stage Y into LDS (+ zero pads enabling the maskless lag loop)
  if (tid < 4) wl2s[600 + tid] = make_float2(0.f, 0.f);
  if (tid < 48) { int c = tid / 6; Yl[c][600 + tid % 6] = make_float2(0.f, 0.f); }
  if (!load_direct) {
    const float4* Yg = (const float4*)(Yt + (size_t)bf * (Cc * Tt));
    for (int i = tid; i < Cc * Tt / 2; i += 512) {
      float4 v = Yg[i];
      int c = i / (Tt / 2), t2 = (i % (Tt / 2)) * 2;
      *(float4*)&Yl[c][t2] = v;        // 16B aligned: 606*c + t2 even
    }
  } else {
    for (int i = tid; i < Cc * Tt; i += 512) {
      int c = i / Tt, t = i % Tt;
      size_t idx = (((size_t)b * Tt + t) * Cc + c) * Ff + f;
      Yl[c][t] = make_float2(in_re[idx], in_im[idx]);
    }
  }
  __syncthreads();

  const v2f* Yd = (const v2f*)&Yl[d][0];
  const v2f* Ye = (const v2f*)&Yl[e][0];
  const v2f* wl2 = (const v2f*)&wl2s[0];

  int aA = (AEND * tg) >> 2;
  int aB = (AEND * (tg + 1)) >> 2;

  for (int iter = 0; iter < 3; ++iter) {
    // ---- weights (iter 0 from Y); iter 1: apply filter -> weights; iter 2: apply -> store
    // wl2[t<7] forced to 0: unused by consumers, required as the lag-loop pad.
    if (iter == 0) {
      for (int t = tid; t < Tt; t += 512) {
        float s = 0.f;
#pragma unroll
        for (int c = 0; c < Cc; ++c) { float2 y = Yl[c][t]; s += y.x*y.x + y.y*y.y; }
        float w = (t < 7) ? 0.f : 1.0f / fmaxf(s * 0.125f, EPSF);
        wl2s[t] = make_float2(w, w);
      }
    } else {
      int il = (iter == 2 && store_direct) ? ilens[b] : Tt;
      for (int t = at2; t < Tt; t += 256) {
        v2f acc[4];
#pragma unroll
        for (int j = 0; j < 4; ++j) acc[j] = *(const v2f*)&Yl[4*ah + j][t];
        for (int p = 0; p < TAPS; ++p) {
          int ts = t - DELAY - p;
          if (ts < 0) break;   // zero-padded region
#pragma unroll
          for (int dd = 0; dd < Cc; ++dd) {
            v2f u2 = *(const v2f*)&Yl[dd][ts];
            v2f us = u2.yx;
            const float4* gq = &Gp[p * Cc + dd][4 * ah];
#pragma unroll
            for (int j = 0; j < 4; ++j) {
              float4 g4 = gq[j];
              v2f gA; gA.x = g4.x; gA.y = g4.y;
              v2f gB; gB.x = g4.z; gB.y = g4.w;
              acc[j] = PKFMA(gA, u2, acc[j]);
              acc[j] = PKFMA(gB, us, acc[j]);
            }
          }
        }
        if (iter == 1) {
          float s = 0.f;
#pragma unroll
          for (int j = 0; j < 4; ++j) s += acc[j].x*acc[j].x + acc[j].y*acc[j].y;
          s += __shfl_xor(s, 1);               // partner lane: other 4 channels
          if (ah == 0) {
            float w = (t < 7) ? 0.f : 1.0f / fmaxf(s * 0.125f, EPSF);
            wl2s[t] = make_float2(w, w);
          }
        } else {
          if (!store_direct) {
            float2* Eg = enh + (size_t)bf * (Cc * Tt);
#pragma unroll
            for (int j = 0; j < 4; ++j)
              Eg[(4*ah + j) * Tt + t] = make_float2(acc[j].x, acc[j].y);
          } else {
            bool live = (t < il);
#pragma unroll
            for (int j = 0; j < 4; ++j) {
              float vx = live ? acc[j].x : 0.f, vy = live ? acc[j].y : 0.f;
              size_t idx = (((size_t)b * Tt + t) * Cc + (4*ah + j)) * Ff + f;
              out_re[idx] = vx;
              out_im[idx] = vy;
            }
          }
        }
      }
    }
    if (iter == 2) break;
    __syncthreads();   // (A) wl2 ready; apply-phase Gp reads done

    // ---- accumulate: lag-split packed register subtiles
    v2f racu[12], pac[5];
    if (ls == 0) {
#pragma unroll
      for (int j = 0; j < 12; ++j) racu[j] = (v2f)(0.f);
      accum_lag<0>(Yd, Ye, wl2, aA, aB, racu, pac);
    } else {
#pragma unroll
      for (int j = 0; j < 3; ++j) racu[j] = (v2f)(0.f);
#pragma unroll
      for (int j = 0; j < 5; ++j) pac[j] = (v2f)(0.f);
      accum_lag<1>(Yd, Ye, wl2, aA, aB, racu, pac);
    }

    // ---- merge the 4 a-group partials; the two lag-sets write DISJOINT RP
    // regions (ids 0..11 vs ids 12..14 + P cols) so they go concurrently.
    // Pass 0 writes (EPS folded onto the diagonal); no FP atomics.
    for (int gp = 0; gp < 4; ++gp) {
      if (tg == gp) {
        if (ls == 0) {
          if (gp == 0) {
#pragma unroll
            for (int id = 0; id < 12; ++id) {
              float2 v = make_float2(racu[id].x, racu[id].y);
              if (id < 5 && d == e) v.x += EPSF;   // ids 0..4 are diag blocks
              RP[kK15[id]*8 + d][kL15[id]*8 + e] = v;
            }
          } else {
#pragma unroll
            for (int id = 0; id < 12; ++id) {
              float2 v = RP[kK15[id]*8 + d][kL15[id]*8 + e];
              v.x += racu[id].x; v.y += racu[id].y;
              RP[kK15[id]*8 + d][kL15[id]*8 + e] = v;
            }
          }
        } else {
          if (gp == 0) {
#pragma unroll
            for (int j = 0; j < 3; ++j)
              RP[kK15[12+j]*8 + d][kL15[12+j]*8 + e] =
                  make_float2(racu[j].x, racu[j].y);
#pragma unroll
            for (int k = 0; k < 5; ++k)
              RP[k*8 + d][KC + e] = make_float2(pac[k].x, pac[k].y);
          } else {
#pragma unroll
            for (int j = 0; j < 3; ++j) {
              float2 v = RP[kK15[12+j]*8 + d][kL15[12+j]*8 + e];
              v.x += racu[j].x; v.y += racu[j].y;
              RP[kK15[12+j]*8 + d][kL15[12+j]*8 + e] = v;
            }
#pragma unroll
            for (int k = 0; k < 5; ++k) {
              float2 v = RP[k*8 + d][KC + e];
              v.x += pac[k].x; v.y += pac[k].y;
              RP[k*8 + d][KC + e] = v;
            }
          }
        }
      }
      __syncthreads();
    }

    // ---- reconstruct the upper triangle: R[I][J] = conj(R[J][I]) for I<J
    for (int idx = tid; idx < KC * KC; idx += 512) {
      int I = idx / KC, J = idx - I * KC;    // const divisor -> magic mul
      if (I < J) {
        float2 v = RP[J][I];
        RP[I][J] = make_float2(v.x, -v.y);
      }
    }
    __syncthreads();

    // ---- unnormalized Gauss-Jordan on [R | P]: ONE barrier per step, packed.
    // Step j: rows i!=j:  RP[i][k] -= fij * RP[j][k], k>j, via sign-prepped
    // pairs: acc = PKFMA((-fx,-fx), c, acc); acc = PKFMA((fy,-fy), c.yx, acc).
    for (int j = 0; j < KC; ++j) {
      if (tid < 480 && srow != j) {
        float2 pv = RP[j][j];
        float idn = 1.0f / (pv.x*pv.x + pv.y*pv.y);
        float2 lij = RP[srow][j];
        float fx = (lij.x*pv.x + lij.y*pv.y) * idn;
        float fy = (lij.y*pv.x - lij.x*pv.y) * idn;
        v2f fA; fA.x = -fx; fA.y = -fx;
        v2f fB; fB.x = fy;  fB.y = -fy;
        for (int k = j + 1 + scol; k < NC; k += 12) {
          v2f c = *(const v2f*)&RP[j][k];
          v2f acc = *(v2f*)&RP[srow][k];
          acc = PKFMA(fA, c, acc);
          acc = PKFMA(fB, c.yx, acc);
          *(v2f*)&RP[srow][k] = acc;
        }
      }
      __syncthreads();
    }
    // R is now diagonal; X = R^-1 P.  Write the packed, sign-prepared filter
    // table the apply phase consumes: Gp = (-X.x, -X.x, X.y, -X.y).
    if (tid < KC * Cc) {               // 320 entries
      int i = tid >> 3, ee = tid & 7;
      float2 pv = RP[i][i];
      float idn = 1.0f / (pv.x*pv.x + pv.y*pv.y);
      float2 p2 = RP[i][KC + ee];
      float xx = (p2.x*pv.x + p2.y*pv.y) * idn;
      float xy = (p2.y*pv.x - p2.x*pv.y) * idn;
      Gp[i][ee] = make_float4(-xx, -xx, xy, -xy);
    }
    __syncthreads();
  }
}

// (B,F,C,T) float2 -> masked (B,T,C,F) re/im planes
__global__ __launch_bounds__(256) void k_tout(const float2* __restrict__ enh,
                                              const int* __restrict__ ilens,
                                              float* __restrict__ out_re,
                                              float* __restrict__ out_im) {
  __shared__ float2 tile[32][33];
  int t0 = blockIdx.x * 32, f0 = blockIdx.y * 32;
  int b = blockIdx.z >> 3, c = blockIdx.z & 7;
  int tx = threadIdx.x & 31, ty = threadIdx.x >> 5;
#pragma unroll
  for (int ii = 0; ii < 4; ++ii) {
    int f = f0 + ty + 8 * ii, t = t0 + tx;
    if (f < Ff && t < Tt)
      tile[ty + 8 * ii][tx] = enh[(((size_t)b * Ff + f) * Cc + c) * Tt + t];
  }
  __syncthreads();
  int il = ilens[b];
#pragma unroll
  for (int ii = 0; ii < 4; ++ii) {
    int t = t0 + ty + 8 * ii, f = f0 + tx;
    if (t < Tt && f < Ff) {
      float2 v = tile[tx][ty + 8 * ii];
      if (t >= il) v = make_float2(0.f, 0.f);
      size_t idx = (((size_t)b * Tt + t) * Cc + c) * Ff + f;
      out_re[idx] = v.x;
      out_im[idx] = v.y;
    }
  }
}

extern "C" void kernel_launch(void* const* d_in, const int* in_sizes, int n_in,
                              void* d_out, int out_size, void* d_ws, size_t ws_size,
                              hipStream_t stream) {
  const float* in_re = (const float*)d_in[0];
  const float* in_im = (const float*)d_in[1];
  const int* ilens = (const int*)d_in[2];
  float* out_re = (float*)d_out;
  float* out_im = out_re + NTOT;

  size_t ybytes = (size_t)Bb * Ff * Cc * Tt * sizeof(float2);  // 78,950,400 B
  int have_yt = ws_size >= ybytes;
  // enh ALIASES Yt: k_wpe block bf stages Yt[bf] into LDS before writing enh[bf],
  // and no block touches another block's slice -> race-free, halves ws need.
  float2* Yt  = (float2*)d_ws;
  float2* enh = (float2*)d_ws;

  if (have_yt) {
    dim3 g((Ff + 31) / 32, (Tt + 31) / 32, Bb * Cc);
    k_tin<<<g, dim3(256), 0, stream>>>(in_re, in_im, Yt);
  }
  {
    dim3 g(Bb * Ff);
    k_wpe<<<g, dim3(512), 0, stream>>>(Yt, enh, in_re, in_im, ilens,
                                       out_re, out_im,
                                       have_yt ? 0 : 1, have_yt ? 0 : 1);
  }
  if (have_yt) {
    dim3 g((Tt + 31) / 32, (Ff + 31) / 32, Bb * Cc);
    k_tout<<<g, dim3(256), 0, stream>>>(enh, ilens, out_re, out_im);
  }
}

// Round 13
// 655.129 us; speedup vs baseline: 1.1923x; 1.1923x over previous
//
#include <hip/hip_runtime.h>
#include <hip/hip_bf16.h>

#define Bb 8
#define Tt 600
#define Cc 8
#define Ff 257
#define TAPS 5
#define DELAY 3
#define KC 40            // TAPS*C
#define NC 48            // KC + C (R columns | P columns)
#define RPW 51           // RP row stride (float2): 102 dw, gcd(102%32=6,32)=2 -> 16-bank spread
#define TQ 593           // T - DELAY - TAPS + 1
#define TP 606           // Yl row stride (float2): d*28%32 all-distinct, conflict-free
#define WLN 604          // wl2 with zero pads [600..603] (max read index 603)
#define AEND 597         // TQ + 4: lag-product a-range
#define EPSF 1e-10f
#define NTOT (Bb*Tt*Cc*Ff)   // 9,868,800

// Native 2-float vector so the backend emits v_pk_fma_f32 (VOP3P packed FP32).
typedef float v2f __attribute__((ext_vector_type(2)));

#if __has_builtin(__builtin_elementwise_fma)
#define PKFMA(a, b, c) __builtin_elementwise_fma((a), (b), (c))
#else
__device__ __forceinline__ v2f pkfma_(v2f a, v2f b, v2f c) {
  v2f r; r.x = fmaf(a.x, b.x, c.x); r.y = fmaf(a.y, b.y, c.y); return r;
}
#define PKFMA(a, b, c) pkfma_((a), (b), (c))
#endif

// p = conj(yd)*yv with yd pre-split: ydxx = yd.xx, ydn = (yd.y, -yd.y)
__device__ __forceinline__ v2f conjmul2(v2f ydxx, v2f ydn, v2f yv) {
  return PKFMA(ydn, yv.yx, ydxx * yv);
}

// Lower-triangle tap-block tables: id -> (k,l), grouped by lag tau=k-l.
constexpr int kABASE[5] = {0, 5, 9, 12, 14};
constexpr int kK15[15] = {0,1,2,3,4, 1,2,3,4, 2,3,4, 3,4, 4};
constexpr int kL15[15] = {0,1,2,3,4, 0,1,2,3, 0,1,2, 0,1, 0};

// Lag-product accumulation (packed).  Two lag-sets across wave pairs:
//   SET 0: tau 0..2 -> 12 R-blocks;  SET 1: tau 3..7 -> 3 R-blocks + 5 P.
// w comes from a RING of 8 register pairs (1 LDS load/a-step instead of 5;
// &7 indices fold at compile time under the 8x unroll since i steps by 8).
// Zero-padded wl2 ([0..6], [600..603]) + Yl tail zeros make range ends vanish.
template<int SET>
__device__ __forceinline__ void accum_lag(const v2f* __restrict__ Yd,
                                          const v2f* __restrict__ Ye,
                                          const v2f* __restrict__ wl2,
                                          int aA, int aB,
                                          v2f (&racu)[12], v2f (&pac)[5]) {
  constexpr int YEM = (SET == 0) ? 3 : 7;   // ye ring mask (span 4 / span 8)
  v2f ye[YEM + 1];
  v2f w8r[8];
  if constexpr (SET == 0) {
#pragma unroll
    for (int j = 0; j < 3; ++j) ye[j] = Ye[aA + j];
  } else {
#pragma unroll
    for (int j = 3; j < 7; ++j) ye[j & YEM] = Ye[aA + j];
  }
#pragma unroll
  for (int j = 3; j < 7; ++j) w8r[j & 7] = wl2[aA + j];

  int len = aB - aA;
  int i = 0;
  for (; i + 8 <= len; i += 8) {
#pragma unroll
    for (int u = 0; u < 8; ++u) {            // full unroll: all &-indices fold
      int a_ = aA + i + u;
      v2f yd_ = Yd[a_];
      w8r[(u + 7) & 7] = wl2[a_ + 7];
      v2f ydxx = yd_.xx;
      v2f ydn; ydn.x = yd_.y; ydn.y = -yd_.y;
      if constexpr (SET == 0) {
        ye[(u + 3) & YEM] = Ye[a_ + 3];
#pragma unroll
        for (int tau = 0; tau <= 2; ++tau) {
          v2f p = conjmul2(ydxx, ydn, ye[(u + tau) & YEM]);
#pragma unroll
          for (int k = tau; k < 5; ++k) {
            int id = kABASE[tau] + (k - tau);
            racu[id] = PKFMA(w8r[(u + 3 + k) & 7], p, racu[id]);
          }
        }
      } else {
        ye[(u + 7) & YEM] = Ye[a_ + 7];
#pragma unroll
        for (int tau = 3; tau <= 7; ++tau) {
          v2f p = conjmul2(ydxx, ydn, ye[(u + tau) & YEM]);
          if (tau == 3) {
            racu[0] = PKFMA(w8r[(u + 6) & 7], p, racu[0]);   // id 12: (3,0)
            racu[1] = PKFMA(w8r[(u + 7) & 7], p, racu[1]);   // id 13: (4,1)
          }
          if (tau == 4) racu[2] = PKFMA(w8r[(u + 7) & 7], p, racu[2]);  // id 14
          pac[tau - 3] = PKFMA(w8r[(u + tau) & 7], p, pac[tau - 3]);
        }
      }
    }
  }
  for (; i < len; ++i) {                     // tail <=7: direct LDS reads
    int a = aA + i;
    v2f yd = Yd[a];
    v2f ydxx = yd.xx;
    v2f ydn; ydn.x = yd.y; ydn.y = -yd.y;
    if constexpr (SET == 0) {
#pragma unroll
      for (int tau = 0; tau <= 2; ++tau) {
        v2f p = conjmul2(ydxx, ydn, Ye[a + tau]);
#pragma unroll
        for (int k = tau; k < 5; ++k) {
          int id = kABASE[tau] + (k - tau);
          racu[id] = PKFMA(wl2[a + 3 + k], p, racu[id]);
        }
      }
    } else {
#pragma unroll
      for (int tau = 3; tau <= 7; ++tau) {
        v2f p = conjmul2(ydxx, ydn, Ye[a + tau]);
        if (tau == 3) {
          racu[0] = PKFMA(wl2[a + 6], p, racu[0]);
          racu[1] = PKFMA(wl2[a + 7], p, racu[1]);
        }
        if (tau == 4) racu[2] = PKFMA(wl2[a + 7], p, racu[2]);
        pac[tau - 3] = PKFMA(wl2[a + tau], p, pac[tau - 3]);
      }
    }
  }
}

// SINGLE-KERNEL WPE: one block (512 thr) per (b,f), full 2-iteration WPE,
// reading the (B,T,C,F) planes directly and writing masked planes directly.
// No transpose kernels: the XCD-chunked swizzle puts the 16 consecutive-f
// blocks that share each 64B plane line on the SAME XCD L2 concurrently, so
// scattered reads dedup in L2 (measured amp 1.15x, r3/r4) and the amplified
// write stream is fire-and-forget (r4: +3 us vs staged mode).
// Accumulation: 8 waves = 4 a-groups x 2 lag-sets, packed FP32, w-ring;
// apply: 2 threads per t (4 channels each); packed sign-prepped solve.
__global__ void __launch_bounds__(512, 4)
__attribute__((amdgpu_waves_per_eu(4, 4)))
k_wpe(const float* __restrict__ in_re,
      const float* __restrict__ in_im,
      const int* __restrict__ ilens,
      float* __restrict__ out_re,
      float* __restrict__ out_im) {
  __shared__ float2 Yl[Cc][TP];        // 8 x 606 complex = 38784 B
  __shared__ float2 RP[KC][RPW];       // [R | P] 40 x 51  = 16320 B
  __shared__ float2 wl2s[WLN];         // (w,w) pairs       =  4832 B
  __shared__ float4 Gp[KC][Cc];        // packed filter     =  5120 B -> 65056 B

  // XCD-chunked bijective swizzle (2056 % 8 == 0): bf = (orig%8)*257 + orig/8
  int orig = blockIdx.x;
  int bf = (orig & 7) * (Bb * Ff / 8) + (orig >> 3);
  int b = bf / Ff, f = bf % Ff;
  int tid = threadIdx.x;               // 0..511
  int group = tid >> 6;                // wave id
  int lane = tid & 63;
  int d = lane & 7;                    // row channel
  int e = lane >> 3;                   // col channel
  int tg = group >> 1;                 // a-group 0..3
  int ls = group & 1;                  // lag-set: 0 -> tau 0..2, 1 -> tau 3..7

  // apply mapping: 2 threads per t, 4 output channels each
  int ah = tid & 1;                    // channel half: ee in [4*ah, 4*ah+4)
  int at2 = tid >> 1;                  // t-stripe 0..255

  // solve mapping: thread = (row, col-chunk), 480 active
  int srow = tid % KC;                 // const divisor -> magic mul, hoisted
  int scol = tid / KC;                 // 0..12

  // ---- stage Y into LDS directly from the (B,T,C,F) planes
  //      (+ zero pads enabling the maskless lag loop)
  if (tid < 4) wl2s[600 + tid] = make_float2(0.f, 0.f);
  if (tid < 48) { int c = tid / 6; Yl[c][600 + tid % 6] = make_float2(0.f, 0.f); }
  for (int i = tid; i < Cc * Tt; i += 512) {
    int c = i / Tt, t = i % Tt;
    size_t idx = (((size_t)b * Tt + t) * Cc + c) * Ff + f;
    Yl[c][t] = make_float2(in_re[idx], in_im[idx]);
  }
  __syncthreads();

  const v2f* Yd = (const v2f*)&Yl[d][0];
  const v2f* Ye = (const v2f*)&Yl[e][0];
  const v2f* wl2 = (const v2f*)&wl2s[0];

  int aA = (AEND * tg) >> 2;
  int aB = (AEND * (tg + 1)) >> 2;

  for (int iter = 0; iter < 3; ++iter) {
    // ---- weights (iter 0 from Y); iter 1: apply filter -> weights; iter 2: apply -> store
    // wl2[t<7] forced to 0: unused by consumers, required as the lag-loop pad.
    if (iter == 0) {
      for (int t = tid; t < Tt; t += 512) {
        float s = 0.f;
#pragma unroll
        for (int c = 0; c < Cc; ++c) { float2 y = Yl[c][t]; s += y.x*y.x + y.y*y.y; }
        float w = (t < 7) ? 0.f : 1.0f / fmaxf(s * 0.125f, EPSF);
        wl2s[t] = make_float2(w, w);
      }
    } else {
      int il = (iter == 2) ? ilens[b] : Tt;
      for (int t = at2; t < Tt; t += 256) {
        v2f acc[4];
#pragma unroll
        for (int j = 0; j < 4; ++j) acc[j] = *(const v2f*)&Yl[4*ah + j][t];
        for (int p = 0; p < TAPS; ++p) {
          int ts = t - DELAY - p;
          if (ts < 0) break;   // zero-padded region
#pragma unroll
          for (int dd = 0; dd < Cc; ++dd) {
            v2f u2 = *(const v2f*)&Yl[dd][ts];
            v2f us = u2.yx;
            const float4* gq = &Gp[p * Cc + dd][4 * ah];
#pragma unroll
            for (int j = 0; j < 4; ++j) {
              float4 g4 = gq[j];
              v2f gA; gA.x = g4.x; gA.y = g4.y;
              v2f gB; gB.x = g4.z; gB.y = g4.w;
              acc[j] = PKFMA(gA, u2, acc[j]);
              acc[j] = PKFMA(gB, us, acc[j]);
            }
          }
        }
        if (iter == 1) {
          float s = 0.f;
#pragma unroll
          for (int j = 0; j < 4; ++j) s += acc[j].x*acc[j].x + acc[j].y*acc[j].y;
          s += __shfl_xor(s, 1);               // partner lane: other 4 channels
          if (ah == 0) {
            float w = (t < 7) ? 0.f : 1.0f / fmaxf(s * 0.125f, EPSF);
            wl2s[t] = make_float2(w, w);
          }
        } else {
          bool live = (t < il);
#pragma unroll
          for (int j = 0; j < 4; ++j) {
            float vx = live ? acc[j].x : 0.f, vy = live ? acc[j].y : 0.f;
            size_t idx = (((size_t)b * Tt + t) * Cc + (4*ah + j)) * Ff + f;
            out_re[idx] = vx;
            out_im[idx] = vy;
          }
        }
      }
    }
    if (iter == 2) break;
    __syncthreads();   // (A) wl2 ready; apply-phase Gp reads done

    // ---- accumulate: lag-split packed register subtiles
    v2f racu[12], pac[5];
    if (ls == 0) {
#pragma unroll
      for (int j = 0; j < 12; ++j) racu[j] = (v2f)(0.f);
      accum_lag<0>(Yd, Ye, wl2, aA, aB, racu, pac);
    } else {
#pragma unroll
      for (int j = 0; j < 3; ++j) racu[j] = (v2f)(0.f);
#pragma unroll
      for (int j = 0; j < 5; ++j) pac[j] = (v2f)(0.f);
      accum_lag<1>(Yd, Ye, wl2, aA, aB, racu, pac);
    }

    // ---- merge the 4 a-group partials; the two lag-sets write DISJOINT RP
    // regions (ids 0..11 vs ids 12..14 + P cols) so they go concurrently.
    // Pass 0 writes (EPS folded onto the diagonal); no FP atomics.
    for (int gp = 0; gp < 4; ++gp) {
      if (tg == gp) {
        if (ls == 0) {
          if (gp == 0) {
#pragma unroll
            for (int id = 0; id < 12; ++id) {
              float2 v = make_float2(racu[id].x, racu[id].y);
              if (id < 5 && d == e) v.x += EPSF;   // ids 0..4 are diag blocks
              RP[kK15[id]*8 + d][kL15[id]*8 + e] = v;
            }
          } else {
#pragma unroll
            for (int id = 0; id < 12; ++id) {
              float2 v = RP[kK15[id]*8 + d][kL15[id]*8 + e];
              v.x += racu[id].x; v.y += racu[id].y;
              RP[kK15[id]*8 + d][kL15[id]*8 + e] = v;
            }
          }
        } else {
          if (gp == 0) {
#pragma unroll
            for (int j = 0; j < 3; ++j)
              RP[kK15[12+j]*8 + d][kL15[12+j]*8 + e] =
                  make_float2(racu[j].x, racu[j].y);
#pragma unroll
            for (int k = 0; k < 5; ++k)
              RP[k*8 + d][KC + e] = make_float2(pac[k].x, pac[k].y);
          } else {
#pragma unroll
            for (int j = 0; j < 3; ++j) {
              float2 v = RP[kK15[12+j]*8 + d][kL15[12+j]*8 + e];
              v.x += racu[j].x; v.y += racu[j].y;
              RP[kK15[12+j]*8 + d][kL15[12+j]*8 + e] = v;
            }
#pragma unroll
            for (int k = 0; k < 5; ++k) {
              float2 v = RP[k*8 + d][KC + e];
              v.x += pac[k].x; v.y += pac[k].y;
              RP[k*8 + d][KC + e] = v;
            }
          }
        }
      }
      __syncthreads();
    }

    // ---- reconstruct the upper triangle: R[I][J] = conj(R[J][I]) for I<J
    for (int idx = tid; idx < KC * KC; idx += 512) {
      int I = idx / KC, J = idx - I * KC;    // const divisor -> magic mul
      if (I < J) {
        float2 v = RP[J][I];
        RP[I][J] = make_float2(v.x, -v.y);
      }
    }
    __syncthreads();

    // ---- unnormalized Gauss-Jordan on [R | P]: ONE barrier per step, packed.
    // Step j: rows i!=j:  RP[i][k] -= fij * RP[j][k], k>j, via sign-prepped
    // pairs: acc = PKFMA((-fx,-fx), c, acc); acc = PKFMA((fy,-fy), c.yx, acc).
    for (int j = 0; j < KC; ++j) {
      if (tid < 480 && srow != j) {
        float2 pv = RP[j][j];
        float idn = 1.0f / (pv.x*pv.x + pv.y*pv.y);
        float2 lij = RP[srow][j];
        float fx = (lij.x*pv.x + lij.y*pv.y) * idn;
        float fy = (lij.y*pv.x - lij.x*pv.y) * idn;
        v2f fA; fA.x = -fx; fA.y = -fx;
        v2f fB; fB.x = fy;  fB.y = -fy;
        for (int k = j + 1 + scol; k < NC; k += 12) {
          v2f c = *(const v2f*)&RP[j][k];
          v2f acc = *(v2f*)&RP[srow][k];
          acc = PKFMA(fA, c, acc);
          acc = PKFMA(fB, c.yx, acc);
          *(v2f*)&RP[srow][k] = acc;
        }
      }
      __syncthreads();
    }
    // R is now diagonal; X = R^-1 P.  Write the packed, sign-prepared filter
    // table the apply phase consumes: Gp = (-X.x, -X.x, X.y, -X.y).
    if (tid < KC * Cc) {               // 320 entries
      int i = tid >> 3, ee = tid & 7;
      float2 pv = RP[i][i];
      float idn = 1.0f / (pv.x*pv.x + pv.y*pv.y);
      float2 p2 = RP[i][KC + ee];
      float xx = (p2.x*pv.x + p2.y*pv.y) * idn;
      float xy = (p2.y*pv.x - p2.x*pv.y) * idn;
      Gp[i][ee] = make_float4(-xx, -xx, xy, -xy);
    }
    __syncthreads();
  }
}

extern "C" void kernel_launch(void* const* d_in, const int* in_sizes, int n_in,
                              void* d_out, int out_size, void* d_ws, size_t ws_size,
                              hipStream_t stream) {
  const float* in_re = (const float*)d_in[0];
  const float* in_im = (const float*)d_in[1];
  const int* ilens = (const int*)d_in[2];
  float* out_re = (float*)d_out;
  float* out_im = out_re + NTOT;

  // Single-kernel direct mode: no workspace, no transpose kernels.
  dim3 g(Bb * Ff);
  k_wpe<<<g, dim3(512), 0, stream>>>(in_re, in_im, ilens, out_re, out_im);
}